// Round 13
// baseline (135.959 us; speedup 1.0000x reference)
//
#include <hip/hip_runtime.h>
#include <hip/hip_fp16.h>

typedef _Float16 f16;
typedef __fp16 fp16x2 __attribute__((ext_vector_type(2)));
typedef _Float16 f16x4 __attribute__((ext_vector_type(4)));
typedef _Float16 f16x8 __attribute__((ext_vector_type(8)));
typedef float f32x4 __attribute__((ext_vector_type(4)));
typedef float f32x16 __attribute__((ext_vector_type(16)));

#define L_SEQ 4096
#define D_MODEL 512
#define KVSPLIT 4
#define C_SCALE 0.18033688f   // 0.125 * log2(e), folded into Q projection

template <typename T, typename F>
__device__ __forceinline__ T bitcast(F x) { return __builtin_bit_cast(T, x); }

__device__ __forceinline__ void gload16(const void* g, void* l) {
  __builtin_amdgcn_global_load_lds((const __attribute__((address_space(1))) void*)g,
                                   (__attribute__((address_space(3))) void*)l, 16, 0, 0);
}

// ---------------- f32 -> f16 for x + 3 projection weights (wq scaled by C) ------------
__global__ void cvt4_kernel(const float* __restrict__ s0, const float* __restrict__ s1,
                            const float* __restrict__ s2, const float* __restrict__ s3,
                            f16* __restrict__ d0, f16* __restrict__ d1,
                            f16* __restrict__ d2, f16* __restrict__ d3) {
  const float* s; f16* d; int n4; float sc = 1.0f;
  switch (blockIdx.z) {
    case 0: s = s0; d = d0; n4 = 524288; break;
    case 1: s = s1; d = d1; n4 = 65536; sc = C_SCALE; break;
    case 2: s = s2; d = d2; n4 = 65536; break;
    default: s = s3; d = d3; n4 = 65536; break;
  }
  for (int i = blockIdx.x * 256 + threadIdx.x; i < n4; i += 131072) {
    float4 v = ((const float4*)s)[i];
    f16x4 o;
    o[0] = (f16)(v.x * sc); o[1] = (f16)(v.y * sc);
    o[2] = (f16)(v.z * sc); o[3] = (f16)(v.w * sc);
    ((f16x4*)d)[i] = o;
  }
}

// ---------------- 512x512 f32 -> transposed f16 (4 matrices) ----------------
__global__ void transpose4_kernel(
    const float* __restrict__ s0, const float* __restrict__ s1,
    const float* __restrict__ s2, const float* __restrict__ s3,
    f16* __restrict__ d0, f16* __restrict__ d1, f16* __restrict__ d2, f16* __restrict__ d3)
{
  const float* s; f16* d;
  switch (blockIdx.z) {
    case 0: s = s0; d = d0; break;
    case 1: s = s1; d = d1; break;
    case 2: s = s2; d = d2; break;
    default: s = s3; d = d3; break;
  }
  __shared__ float tl[32][33];
  const int bx = blockIdx.x * 32, by = blockIdx.y * 32;
  const int tx = threadIdx.x, ty = threadIdx.y;
  #pragma unroll
  for (int i = 0; i < 4; ++i)
    tl[ty + i * 8][tx] = s[(size_t)(by + ty + i * 8) * 512 + bx + tx];
  __syncthreads();
  #pragma unroll
  for (int i = 0; i < 4; ++i)
    d[(size_t)(bx + ty + i * 8) * 512 + by + tx] = (f16)tl[tx][ty + i * 8];
}

// ---------------- GEMM core: C[M,N] = A[M,K] @ B[K,N] (+bias), BT given [N,K] ----------
// MODE 0: f16 out; MODE 1: f16 transposed out [N,M]; MODE 2: f32 out; MODE 3: f16 out, no bias
template<int MODE, int BM>
__device__ __forceinline__ void gemm_core(
    const f16* __restrict__ A, const f16* __restrict__ BT,
    const float* __restrict__ bias, void* __restrict__ Cv,
    int M, int N, int K, f16* As, f16* Bs)
{
  constexpr int MI = BM / 32;
  const int t = threadIdx.x;
  const int w = t >> 6;
  const int bm = blockIdx.x * BM, bn = blockIdx.y * 64;
  const int m0 = (w >> 1) * (BM / 2), n0 = (w & 1) * 32;
  const int lane = t & 63, lr = lane & 15, lg = lane >> 4;

  f32x4 zf = {0.f, 0.f, 0.f, 0.f};
  f32x4 acc[MI][2];
  #pragma unroll
  for (int i = 0; i < MI; ++i)
    #pragma unroll
    for (int j = 0; j < 2; ++j)
      acc[i][j] = zf;

  const int arow = t >> 2, achk = t & 3;
  const f16* gA = A + (size_t)(bm + arow) * K + achk * 8;
  const f16* gB = BT + (size_t)(bn + arow) * K + achk * 8;
  f16* lA = As + w * 512;
  f16* lB = Bs + w * 512;

  for (int k0 = 0; k0 < K; k0 += 32) {
    gload16(gA + k0, lA);
    if constexpr (BM == 128) gload16(gA + (size_t)64 * K + k0, lA + 2048);
    gload16(gB + k0, lB);
    __syncthreads();
    f16x8 af[MI], bfv[2];
    #pragma unroll
    for (int i = 0; i < MI; ++i)
      af[i] = *(const f16x8*)&As[(m0 + i * 16 + lr) * 32 + lg * 8];
    #pragma unroll
    for (int j = 0; j < 2; ++j)
      bfv[j] = *(const f16x8*)&Bs[(n0 + j * 16 + lr) * 32 + lg * 8];
    #pragma unroll
    for (int i = 0; i < MI; ++i)
      #pragma unroll
      for (int j = 0; j < 2; ++j)
        acc[i][j] = __builtin_amdgcn_mfma_f32_16x16x32_f16(af[i], bfv[j], acc[i][j], 0, 0, 0);
    __syncthreads();
  }

  #pragma unroll
  for (int j = 0; j < 2; ++j) {
    const int gn = bn + n0 + j * 16 + lr;
    const float bv = (MODE == 3) ? 0.f : bias[gn];
    #pragma unroll
    for (int i = 0; i < MI; ++i) {
      const int gmb = bm + m0 + i * 16 + lg * 4;
      if constexpr (MODE == 0 || MODE == 3) {
        f16* C = (f16*)Cv;
        #pragma unroll
        for (int r = 0; r < 4; ++r)
          C[(size_t)(gmb + r) * N + gn] = (f16)(acc[i][j][r] + bv);
      } else if constexpr (MODE == 1) {
        f16* C = (f16*)Cv;   // [N, M]
        f16x4 u;
        u[0] = (f16)(acc[i][j][0] + bv);
        u[1] = (f16)(acc[i][j][1] + bv);
        u[2] = (f16)(acc[i][j][2] + bv);
        u[3] = (f16)(acc[i][j][3] + bv);
        *(f16x4*)&C[(size_t)gn * M + gmb] = u;
      } else {
        float* C = (float*)Cv;
        #pragma unroll
        for (int r = 0; r < 4; ++r)
          C[(size_t)(gmb + r) * N + gn] = acc[i][j][r] + bv;
      }
    }
  }
}

template<int MODE, int BM>
__global__ __launch_bounds__(256) void gemm_bt_kernel(
    const f16* __restrict__ A, const f16* __restrict__ BT,
    const float* __restrict__ bias, void* __restrict__ Cv, int M, int N, int K)
{
  __shared__ __attribute__((aligned(16))) f16 As[BM * 32];
  __shared__ __attribute__((aligned(16))) f16 Bs[64 * 32];
  gemm_core<MODE, BM>(A, BT, bias, Cv, M, N, K, As, Bs);
}

// ---------------- combined-weight GEMMs: W'T = qpT @ wq16 (3x, z-indexed) -------------
__global__ __launch_bounds__(256) void wcombine_kernel(
    const f16* __restrict__ qpT, const f16* __restrict__ kpT, const f16* __restrict__ vpT,
    const f16* __restrict__ wq16, const f16* __restrict__ wk16, const f16* __restrict__ wv16,
    f16* __restrict__ WqT, f16* __restrict__ WkT, f16* __restrict__ WvT)
{
  __shared__ __attribute__((aligned(16))) f16 As[128 * 32];
  __shared__ __attribute__((aligned(16))) f16 Bs[64 * 32];
  const f16* A; const f16* B; f16* C;
  switch (blockIdx.z) {
    case 0: A = qpT; B = wq16; C = WqT; break;
    case 1: A = kpT; B = wk16; C = WkT; break;
    default: A = vpT; B = wv16; C = WvT; break;
  }
  gemm_core<3, 128>(A, B, nullptr, C, 512, 512, 512, As, Bs);
}

// ---------------- combined biases: bc[z] = b1 @ W2 + b2 (q scaled by C) ---------------
__global__ void bcombine_kernel(
    const float* __restrict__ wq_b, const float* __restrict__ wk_b, const float* __restrict__ wv_b,
    const f16* __restrict__ qpT, const f16* __restrict__ kpT, const f16* __restrict__ vpT,
    const float* __restrict__ qp_b, const float* __restrict__ kp_b, const float* __restrict__ vp_b,
    float* __restrict__ bc)
{
  const float* b1; const f16* WT; const float* b2;
  switch (blockIdx.z) {
    case 0: b1 = wq_b; WT = qpT; b2 = qp_b; break;
    case 1: b1 = wk_b; WT = kpT; b2 = kp_b; break;
    default: b1 = wv_b; WT = vpT; b2 = vp_b; break;
  }
  const int o = blockIdx.x * 256 + threadIdx.x;
  const f16* row = WT + (size_t)o * 512;
  float s = 0.f;
  #pragma unroll 8
  for (int m = 0; m < 512; ++m)
    s += b1[m] * (float)row[m];
  const float sc = (blockIdx.z == 0) ? C_SCALE : 1.0f;
  bc[blockIdx.z * 512 + o] = (s + b2[o]) * sc;
}

// ---------------- fused QKV projection (z = 0:q, 1:k, 2:v-transposed) ----------------
__global__ __launch_bounds__(256) void gemm_qkv_kernel(
    const f16* __restrict__ x,
    const f16* __restrict__ WqT, const f16* __restrict__ WkT, const f16* __restrict__ WvT,
    const float* __restrict__ bc,
    f16* __restrict__ q_f, f16* __restrict__ k_f, f16* __restrict__ vT)
{
  __shared__ __attribute__((aligned(16))) f16 As[128 * 32];
  __shared__ __attribute__((aligned(16))) f16 Bs[64 * 32];
  const int z = blockIdx.z;
  if (z == 2)
    gemm_core<1, 128>(x, WvT, bc + 1024, vT, 4096, 512, 512, As, Bs);
  else if (z == 1)
    gemm_core<0, 128>(x, WkT, bc + 512, k_f, 4096, 512, 512, As, Bs);
  else
    gemm_core<0, 128>(x, WqT, bc, q_f, 4096, 512, 512, As, Bs);
}

// ---------------- sp bias precompute ----------------
// value = log2(1 + 0.5*softmax(sp, axis=-1))   [f16; consumed as exp2 logit offset]
// layout: bt[((q>>5)*128 + (kv>>5))*1024 + ((kv>>4)&1)*512 + (q&31)*16 + (kv&15)]
__global__ __launch_bounds__(512) void sp_bias_kernel(
    const float* __restrict__ spg, f16* __restrict__ bt)
{
  __shared__ __attribute__((aligned(16))) f16 ex[16 * 4104];  // row stride 8208B (16B mult)
  __shared__ float sums[16];
  const int t = threadIdx.x;

  {
    const int row = t >> 5, j = t & 31;
    const float4* srow = (const float4*)(spg + (size_t)(blockIdx.x * 16 + row) * L_SEQ);
    f16* dst = ex + row * 4104;
    float ssum = 0.f;
    #pragma unroll 4
    for (int c = 0; c < 32; ++c) {
      float4 v = srow[c * 32 + j];
      float e0 = __expf(v.x), e1 = __expf(v.y), e2 = __expf(v.z), e3 = __expf(v.w);
      ssum += (e0 + e1) + (e2 + e3);
      f16x4 u;
      u[0] = (f16)e0; u[1] = (f16)e1; u[2] = (f16)e2; u[3] = (f16)e3;
      *(f16x4*)&dst[(c * 32 + j) * 4] = u;
    }
    ssum += __shfl_xor(ssum, 1, 64);
    ssum += __shfl_xor(ssum, 2, 64);
    ssum += __shfl_xor(ssum, 4, 64);
    ssum += __shfl_xor(ssum, 8, 64);
    ssum += __shfl_xor(ssum, 16, 64);
    if (j == 0) sums[row] = ssum;
  }
  __syncthreads();

  const int hi = t & 1, qloc = (t >> 1) & 15, s16 = (t >> 5) & 1;
  const float sc = 0.5f / sums[qloc];
  const int qt5 = blockIdx.x >> 1;
  const int q31 = ((blockIdx.x & 1) << 4) + qloc;
  const f16* exr = ex + qloc * 4104 + s16 * 16 + hi * 8;
  f16* ob = bt + (size_t)qt5 * 131072 + s16 * 512 + q31 * 16 + hi * 8;
  #pragma unroll 4
  for (int i = 0; i < 16; ++i) {
    const int kt5 = (t >> 6) + i * 8;
    f16x8 v = *(const f16x8*)&exr[kt5 * 32];
    f16x8 u;
    #pragma unroll
    for (int e = 0; e < 8; ++e)
      u[e] = (f16)__log2f(fmaf((float)v[e], sc, 1.0f));
    *(f16x8*)&ob[(size_t)kt5 * 1024] = u;
  }
}

// ---------------- fused attention, 32x32x16 MFMA, in-register P ----------------
// grid = 1024 linear blocks; all 8 heads of a (qtile,z) group share id%8 (XCD coloc).
// 4 waves; wave owns 32 q rows. Swapped QK^T + kv-row-permuted K keeps P in-lane.
// Q pre-scaled by 0.125*log2e upstream -> logit = s + L; whole exp path in packed
// f16 (cvt_pkrtz -> hadd2 -> h2exp2), halving the VALU issue per step.
__global__ __launch_bounds__(256, 4) void attn3_kernel(
    const f16* __restrict__ qg, const f16* __restrict__ kg,
    const f16* __restrict__ vTg, const f16* __restrict__ bt,
    f16* __restrict__ opart, float* __restrict__ rspart)
{
  __shared__ __attribute__((aligned(16))) f16 Ks[2 * 4096];
  __shared__ __attribute__((aligned(16))) f16 Vs[2 * 4096];

  const int t = threadIdx.x;
  const int w = t >> 6, lane = t & 63;
  const int l31 = lane & 31, hi = lane >> 5;
  // XCD-coloc decomposition: b = (g%8) + 8*h + 64*(g/8); g = qt + 32*z
  const int b = blockIdx.x;
  const int h = (b >> 3) & 7;
  const int g = (b & 7) + ((b >> 6) << 3);
  const int qt = g & 31;
  const int z = g >> 5;
  const int q0w = qt * 128 + w * 32;
  const int kvbase = z * (L_SEQ / KVSPLIT);
  const int NST = (L_SEQ / KVSPLIT) / 64;

  // Q B-fragments (persist): qf[dk] = (C*Q)[q0w+l31][h*64 + dk*16 + hi*8 ..+8]
  f16x8 qf[4];
  #pragma unroll
  for (int dk = 0; dk < 4; ++dk)
    qf[dk] = *(const f16x8*)&qg[(size_t)(q0w + l31) * D_MODEL + h * 64 + dk * 16 + hi * 8];

  // staging source addresses (XOR-swizzle pre-applied on global side; LDS writes linear)
  const int srow0 = t >> 3, srow1 = 32 + (t >> 3), q16 = t & 7;
  const f16* ksrc0 = kg + h * 64 + (size_t)(kvbase + srow0) * D_MODEL + ((q16 ^ (srow0 & 7)) * 8);
  const f16* ksrc1 = kg + h * 64 + (size_t)(kvbase + srow1) * D_MODEL + ((q16 ^ (srow1 & 7)) * 8);
  const f16* vsrc0 = vTg + (size_t)(h * 64 + srow0) * L_SEQ + kvbase + (q16 ^ (srow0 & 7)) * 8;
  const f16* vsrc1 = vTg + (size_t)(h * 64 + srow1) * L_SEQ + kvbase + (q16 ^ (srow1 & 7)) * 8;

  #define STAGE(buf, stp)                                                      \
    do {                                                                       \
      const size_t ko = (size_t)(stp) * 64 * D_MODEL, vo = (size_t)(stp) * 64; \
      gload16(ksrc0 + ko, &Ks[(buf) * 4096 + w * 512]);                        \
      gload16(ksrc1 + ko, &Ks[(buf) * 4096 + 2048 + w * 512]);                 \
      gload16(vsrc0 + vo, &Vs[(buf) * 4096 + w * 512]);                        \
      gload16(vsrc1 + vo, &Vs[(buf) * 4096 + 2048 + w * 512]);                 \
    } while (0)

  // K A-row permutation: swap bits 2<->3 of l31
  const int sw23 = (l31 & ~12) | ((l31 & 4) << 1) | ((l31 & 8) >> 1);
  const int r7 = sw23 & 7;
  const int krow0 = sw23 * 64, krow1 = krow0 + 2048;        // jj=0 / jj=1 row bases (f16)
  const int vr7 = l31 & 7;
  const int vrow0 = l31 * 64, vrow1 = vrow0 + 2048;         // dg=0 / dg=1

  // bias base: ((qt5*128 + kt5)*2 + s16)*512 + l31*16 + hi*8
  const f16* bb = bt + (size_t)(q0w >> 5) * 131072 + l31 * 16 + hi * 8;
  const int kvb5 = kvbase >> 5;

  f32x16 zz = {0,0,0,0,0,0,0,0,0,0,0,0,0,0,0,0};
  f32x16 o0 = zz, o1 = zz;
  float rs0 = 0.f, rs1 = 0.f;
  const fp16x2 one2 = {(__fp16)1.0f, (__fp16)1.0f};

  STAGE(0, 0);
  __syncthreads();

  for (int st = 0; st < NST; ++st) {
    const int buf = st & 1;

    // ---- 1. bias (log2-domain) loads FIRST (oldest in vmcnt queue) ----
    const f16* bs = bb + (size_t)(kvb5 + st * 2) * 1024;
    f16x8 bl[4];   // [jj*2 + s16]
    bl[0] = *(const f16x8*)(bs);
    bl[1] = *(const f16x8*)(bs + 512);
    bl[2] = *(const f16x8*)(bs + 1024);
    bl[3] = *(const f16x8*)(bs + 1536);
    __builtin_amdgcn_sched_barrier(0);   // pin: bias issue precedes STAGE

    // ---- 2. prefetch next tile (stays in flight past the bias wait) ----
    if (st + 1 < NST) STAGE(buf ^ 1, st + 1);

    // ---- 3. S^T = K @ Q^T (swapped), two 32-kv tiles; s is exp2-ready logit ----
    f32x16 s0 = zz, s1 = zz;
    const f16* kb = &Ks[buf * 4096];
    #pragma unroll
    for (int dk = 0; dk < 4; ++dk) {
      const int ch = ((dk * 2 + hi) ^ r7) * 8;
      f16x8 k0 = *(const f16x8*)&kb[krow0 + ch];
      f16x8 k1 = *(const f16x8*)&kb[krow1 + ch];
      s0 = __builtin_amdgcn_mfma_f32_32x32x16_f16(k0, qf[dk], s0, 0, 0, 0);
      s1 = __builtin_amdgcn_mfma_f32_32x32x16_f16(k1, qf[dk], s1, 0, 0, 0);
    }

    // ---- 4. p = exp2(s + L), fully packed f16; pairs land directly in PV frags ----
    f16x8 pa[4];   // [kk] : kv = kk*16 + hi*8 + e
    #pragma unroll
    for (int q = 0; q < 4; ++q) {
      const f32x16& s = (q >> 1) ? s1 : s0;
      const int sh = q & 1;
      union { f16x8 v; fp16x2 h2[4]; } ub; ub.v = bl[q];
      union { fp16x2 h2[4]; f16x8 v; } up;
      #pragma unroll
      for (int e2 = 0; e2 < 4; ++e2) {
        fp16x2 s2 = __builtin_amdgcn_cvt_pkrtz(s[sh * 8 + e2 * 2], s[sh * 8 + e2 * 2 + 1]);
        __half2 p2 = h2exp2(__hadd2(bitcast<__half2>(s2), bitcast<__half2>(ub.h2[e2])));
        fp16x2 pp = bitcast<fp16x2>(p2);
        up.h2[e2] = pp;
        if (e2 & 1) rs1 = __builtin_amdgcn_fdot2(pp, one2, rs1, false);
        else        rs0 = __builtin_amdgcn_fdot2(pp, one2, rs0, false);
      }
      pa[q] = up.v;
    }

    // ---- 5. O += P @ V ----
    const f16* vb = &Vs[buf * 4096];
    #pragma unroll
    for (int kk = 0; kk < 4; ++kk) {
      const int ch = ((kk * 2 + hi) ^ vr7) * 8;
      f16x8 v0 = *(const f16x8*)&vb[vrow0 + ch];
      f16x8 v1 = *(const f16x8*)&vb[vrow1 + ch];
      o0 = __builtin_amdgcn_mfma_f32_32x32x16_f16(pa[kk], v0, o0, 0, 0, 0);
      o1 = __builtin_amdgcn_mfma_f32_32x32x16_f16(pa[kk], v1, o1, 0, 0, 0);
    }
    __syncthreads();   // drains prefetch (had full exp+PV to land) + buf handoff
  }
  #undef STAGE

  // ---- epilogue: partial O (f16) + partial rowsums ----
  float rs = rs0 + rs1;
  rs += __shfl_xor(rs, 32, 64);
  f16* op = opart + (size_t)z * (L_SEQ * D_MODEL);
  #pragma unroll
  for (int dg = 0; dg < 2; ++dg) {
    const f32x16& o = dg ? o1 : o0;
    #pragma unroll
    for (int r = 0; r < 16; ++r) {
      const int q = q0w + (r & 3) + 8 * (r >> 2) + 4 * hi;
      op[(size_t)q * D_MODEL + h * 64 + dg * 32 + l31] = (f16)o[r];
    }
  }
  if (hi == 0)
    rspart[((size_t)z * 8 + h) * L_SEQ + q0w + l31] = rs;
}

// ---------------- combine kv-split partials -> normalized f16 ----------------
__global__ void combine4_kernel(const f16* __restrict__ opart,
                                const float* __restrict__ rspart,
                                f16* __restrict__ attout)
{
  const int idx = blockIdx.x * 256 + threadIdx.x;  // 262144
  const int q = idx >> 6;
  const int d = (idx & 63) << 3;
  const int h = d >> 6;
  float rsum = 0.f;
  #pragma unroll
  for (int zz = 0; zz < KVSPLIT; ++zz)
    rsum += rspart[((size_t)zz * 8 + h) * L_SEQ + q];
  const float inv = 1.f / rsum;
  float acc[8] = {0,0,0,0,0,0,0,0};
  #pragma unroll
  for (int zz = 0; zz < KVSPLIT; ++zz) {
    f16x8 v = *(const f16x8*)&opart[(size_t)zz * (L_SEQ * D_MODEL) + (size_t)q * D_MODEL + d];
    #pragma unroll
    for (int e = 0; e < 8; ++e) acc[e] += (float)v[e];
  }
  f16x8 u;
  #pragma unroll
  for (int e = 0; e < 8; ++e) u[e] = (f16)(acc[e] * inv);
  *(f16x8*)&attout[(size_t)q * D_MODEL + d] = u;
}

// ---------------- host ----------------
extern "C" void kernel_launch(void* const* d_in, const int* in_sizes, int n_in,
                              void* d_out, int out_size, void* d_ws, size_t ws_size,
                              hipStream_t stream)
{
  (void)in_sizes; (void)n_in; (void)out_size; (void)ws_size;

  const float* x    = (const float*)d_in[0];
  const float* sp   = (const float*)d_in[1];
  const float* wq_w = (const float*)d_in[2];
  const float* wq_b = (const float*)d_in[3];
  const float* wk_w = (const float*)d_in[4];
  const float* wk_b = (const float*)d_in[5];
  const float* wv_w = (const float*)d_in[6];
  const float* wv_b = (const float*)d_in[7];
  const float* qp_w = (const float*)d_in[8];
  const float* qp_b = (const float*)d_in[9];
  const float* kp_w = (const float*)d_in[10];
  const float* kp_b = (const float*)d_in[11];
  const float* vp_w = (const float*)d_in[12];
  const float* vp_b = (const float*)d_in[13];
  const float* out_w = (const float*)d_in[14];
  const float* out_b = (const float*)d_in[15];

  const size_t MB = 1048576;
  char* ws = (char*)d_ws;
  // phase 1 (dead before attn) -- overlapped by opart:
  f16*   x_f    = (f16*)(ws + 0);              // 4 MiB
  f16*   qpT    = (f16*)(ws + 4 * MB);
  f16*   kpT    = (f16*)(ws + 4 * MB + 524288);
  f16*   vpT    = (f16*)(ws + 5 * MB);
  f16*   wq16   = (f16*)(ws + 6 * MB);
  f16*   wk16   = (f16*)(ws + 6 * MB + 524288);
  f16*   wv16   = (f16*)(ws + 7 * MB);
  f16*   WqT    = (f16*)(ws + 7 * MB + 524288);
  f16*   WkT    = (f16*)(ws + 8 * MB);
  f16*   WvT    = (f16*)(ws + 8 * MB + 524288);
  float* bc     = (float*)(ws + 9 * MB);       // 3*512 f32
  // attn phase:
  f16*   opart  = (f16*)(ws + 0);              // 16 MiB (over phase-1 buffers)
  f16*   q_f    = (f16*)(ws + 16 * MB);        // 4 MiB; attout overlays after attn
  f16*   attout = (f16*)(ws + 16 * MB);
  f16*   k_f    = (f16*)(ws + 20 * MB);
  f16*   vT     = (f16*)(ws + 24 * MB);
  float* rspart = (float*)(ws + 28 * MB);      // 512 KiB
  f16*   bt     = (f16*)(ws + 28 * MB + 524288); // 32 MiB -> ends 60.5 MiB
  // outT lives OUTSIDE opart's range (consumed by the FINAL gemm, after attn3
  // has overwritten ws[0..16MB) with opart)
  f16*   outT   = (f16*)(ws + 60 * MB + 524288); // 512 KiB, ends 61 MiB

  cvt4_kernel<<<dim3(512, 1, 4), 256, 0, stream>>>(x, wq_w, wk_w, wv_w,
                                                   x_f, wq16, wk16, wv16);
  transpose4_kernel<<<dim3(16, 16, 4), dim3(32, 8), 0, stream>>>(
      qp_w, kp_w, vp_w, out_w, qpT, kpT, vpT, outT);
  sp_bias_kernel<<<256, 512, 0, stream>>>(sp, bt);

  wcombine_kernel<<<dim3(4, 8, 3), 256, 0, stream>>>(qpT, kpT, vpT,
                                                     wq16, wk16, wv16,
                                                     WqT, WkT, WvT);
  bcombine_kernel<<<dim3(2, 1, 3), 256, 0, stream>>>(wq_b, wk_b, wv_b,
                                                     qpT, kpT, vpT,
                                                     qp_b, kp_b, vp_b, bc);
  gemm_qkv_kernel<<<dim3(32, 8, 3), 256, 0, stream>>>(x_f, WqT, WkT, WvT, bc,
                                                      q_f, k_f, vT);

  attn3_kernel<<<dim3(1024), 256, 0, stream>>>(q_f, k_f, vT, bt,
                                               opart, rspart);
  combine4_kernel<<<1024, 256, 0, stream>>>(opart, rspart, attout);

  gemm_bt_kernel<2, 64><<<dim3(64, 8), 256, 0, stream>>>(attout, outT, out_b,
                                                         d_out, 4096, 512, 512);
}

// Round 14
// 126.015 us; speedup vs baseline: 1.0789x; 1.0789x over previous
//
#include <hip/hip_runtime.h>
#include <hip/hip_fp16.h>

typedef _Float16 f16;
typedef __fp16 fp16x2 __attribute__((ext_vector_type(2)));
typedef _Float16 f16x4 __attribute__((ext_vector_type(4)));
typedef _Float16 f16x8 __attribute__((ext_vector_type(8)));
typedef float f32x4 __attribute__((ext_vector_type(4)));
typedef float f32x16 __attribute__((ext_vector_type(16)));

#define L_SEQ 4096
#define D_MODEL 512
#define KVSPLIT 4
#define C_SCALE 0.18033688f   // 0.125 * log2(e), folded into Q projection

template <typename T, typename F>
__device__ __forceinline__ T bitcast(F x) { return __builtin_bit_cast(T, x); }

__device__ __forceinline__ void gload16(const void* g, void* l) {
  __builtin_amdgcn_global_load_lds((const __attribute__((address_space(1))) void*)g,
                                   (__attribute__((address_space(3))) void*)l, 16, 0, 0);
}

// ---------------- fused prep: f32->f16 cvt (x + 3 weights) AND 4 transposes ----------
// blocks [0,512): x cvt; [512,704): weight cvt (wq scaled); [704,1728): transposes
__global__ __launch_bounds__(256) void prep_kernel(
    const float* __restrict__ x, const float* __restrict__ wq_w,
    const float* __restrict__ wk_w, const float* __restrict__ wv_w,
    const float* __restrict__ qp_w, const float* __restrict__ kp_w,
    const float* __restrict__ vp_w, const float* __restrict__ out_w,
    f16* __restrict__ x_f, f16* __restrict__ wq16,
    f16* __restrict__ wk16, f16* __restrict__ wv16,
    f16* __restrict__ qpT, f16* __restrict__ kpT,
    f16* __restrict__ vpT, f16* __restrict__ outT)
{
  const int bid = blockIdx.x, t = threadIdx.x;
  if (bid < 704) {
    const float* s; f16* d; int i, n4, stride; float sc = 1.0f;
    if (bid < 512) {
      s = x; d = x_f; i = bid * 256 + t; n4 = 524288; stride = 131072;
    } else {
      const int widx = (bid - 512) >> 6;
      s = (widx == 0) ? wq_w : (widx == 1) ? wk_w : wv_w;
      d = (widx == 0) ? wq16 : (widx == 1) ? wk16 : wv16;
      if (widx == 0) sc = C_SCALE;
      i = ((bid - 512) & 63) * 256 + t; n4 = 65536; stride = 16384;
    }
    for (; i < n4; i += stride) {
      float4 v = ((const float4*)s)[i];
      f16x4 o;
      o[0] = (f16)(v.x * sc); o[1] = (f16)(v.y * sc);
      o[2] = (f16)(v.z * sc); o[3] = (f16)(v.w * sc);
      ((f16x4*)d)[i] = o;
    }
  } else {
    __shared__ float tl[32][33];
    const int tt = bid - 704;
    const int mat = tt >> 8, tile = tt & 255;
    const float* s; f16* d;
    switch (mat) {
      case 0: s = qp_w; d = qpT; break;
      case 1: s = kp_w; d = kpT; break;
      case 2: s = vp_w; d = vpT; break;
      default: s = out_w; d = outT; break;
    }
    const int bx = (tile & 15) * 32, by = (tile >> 4) * 32;
    const int tx = t & 31, ty = t >> 5;
    #pragma unroll
    for (int i = 0; i < 4; ++i)
      tl[ty + i * 8][tx] = s[(size_t)(by + ty + i * 8) * 512 + bx + tx];
    __syncthreads();
    #pragma unroll
    for (int i = 0; i < 4; ++i)
      d[(size_t)(bx + ty + i * 8) * 512 + by + tx] = (f16)tl[tx][ty + i * 8];
  }
}

// ---------------- GEMM core: C[M,N] = A[M,K] @ B[K,N] (+bias), BT given [N,K] ----------
// MODE 0: f16 out; MODE 1: f16 transposed out [N,M]; MODE 2: f32 out; MODE 3: f16 out, no bias
template<int MODE, int BM>
__device__ __forceinline__ void gemm_core(
    const f16* __restrict__ A, const f16* __restrict__ BT,
    const float* __restrict__ bias, void* __restrict__ Cv,
    int M, int N, int K, f16* As, f16* Bs)
{
  constexpr int MI = BM / 32;
  const int t = threadIdx.x;
  const int w = t >> 6;
  const int bm = blockIdx.x * BM, bn = blockIdx.y * 64;
  const int m0 = (w >> 1) * (BM / 2), n0 = (w & 1) * 32;
  const int lane = t & 63, lr = lane & 15, lg = lane >> 4;

  f32x4 zf = {0.f, 0.f, 0.f, 0.f};
  f32x4 acc[MI][2];
  #pragma unroll
  for (int i = 0; i < MI; ++i)
    #pragma unroll
    for (int j = 0; j < 2; ++j)
      acc[i][j] = zf;

  const int arow = t >> 2, achk = t & 3;
  const f16* gA = A + (size_t)(bm + arow) * K + achk * 8;
  const f16* gB = BT + (size_t)(bn + arow) * K + achk * 8;
  f16* lA = As + w * 512;
  f16* lB = Bs + w * 512;

  for (int k0 = 0; k0 < K; k0 += 32) {
    gload16(gA + k0, lA);
    if constexpr (BM == 128) gload16(gA + (size_t)64 * K + k0, lA + 2048);
    gload16(gB + k0, lB);
    __syncthreads();
    f16x8 af[MI], bfv[2];
    #pragma unroll
    for (int i = 0; i < MI; ++i)
      af[i] = *(const f16x8*)&As[(m0 + i * 16 + lr) * 32 + lg * 8];
    #pragma unroll
    for (int j = 0; j < 2; ++j)
      bfv[j] = *(const f16x8*)&Bs[(n0 + j * 16 + lr) * 32 + lg * 8];
    #pragma unroll
    for (int i = 0; i < MI; ++i)
      #pragma unroll
      for (int j = 0; j < 2; ++j)
        acc[i][j] = __builtin_amdgcn_mfma_f32_16x16x32_f16(af[i], bfv[j], acc[i][j], 0, 0, 0);
    __syncthreads();
  }

  #pragma unroll
  for (int j = 0; j < 2; ++j) {
    const int gn = bn + n0 + j * 16 + lr;
    const float bv = (MODE == 3) ? 0.f : bias[gn];
    #pragma unroll
    for (int i = 0; i < MI; ++i) {
      const int gmb = bm + m0 + i * 16 + lg * 4;
      if constexpr (MODE == 0 || MODE == 3) {
        f16* C = (f16*)Cv;
        #pragma unroll
        for (int r = 0; r < 4; ++r)
          C[(size_t)(gmb + r) * N + gn] = (f16)(acc[i][j][r] + bv);
      } else if constexpr (MODE == 1) {
        f16* C = (f16*)Cv;   // [N, M]
        f16x4 u;
        u[0] = (f16)(acc[i][j][0] + bv);
        u[1] = (f16)(acc[i][j][1] + bv);
        u[2] = (f16)(acc[i][j][2] + bv);
        u[3] = (f16)(acc[i][j][3] + bv);
        *(f16x4*)&C[(size_t)gn * M + gmb] = u;
      } else {
        float* C = (float*)Cv;
        #pragma unroll
        for (int r = 0; r < 4; ++r)
          C[(size_t)(gmb + r) * N + gn] = acc[i][j][r] + bv;
      }
    }
  }
}

template<int MODE, int BM>
__global__ __launch_bounds__(256) void gemm_bt_kernel(
    const f16* __restrict__ A, const f16* __restrict__ BT,
    const float* __restrict__ bias, void* __restrict__ Cv, int M, int N, int K)
{
  __shared__ __attribute__((aligned(16))) f16 As[BM * 32];
  __shared__ __attribute__((aligned(16))) f16 Bs[64 * 32];
  gemm_core<MODE, BM>(A, BT, bias, Cv, M, N, K, As, Bs);
}

// ------- fused combined-weight GEMMs (z<3) + combined biases (z>=3), one launch -------
__global__ __launch_bounds__(256) void wbcombine_kernel(
    const f16* __restrict__ qpT, const f16* __restrict__ kpT, const f16* __restrict__ vpT,
    const f16* __restrict__ wq16, const f16* __restrict__ wk16, const f16* __restrict__ wv16,
    f16* __restrict__ WqT, f16* __restrict__ WkT, f16* __restrict__ WvT,
    const float* __restrict__ wq_b, const float* __restrict__ wk_b, const float* __restrict__ wv_b,
    const float* __restrict__ qp_b, const float* __restrict__ kp_b, const float* __restrict__ vp_b,
    float* __restrict__ bc)
{
  __shared__ __attribute__((aligned(16))) f16 As[128 * 32];
  __shared__ __attribute__((aligned(16))) f16 Bs[64 * 32];
  const int z = blockIdx.z;
  if (z < 3) {
    const f16* A; const f16* B; f16* C;
    switch (z) {
      case 0: A = qpT; B = wq16; C = WqT; break;
      case 1: A = kpT; B = wk16; C = WkT; break;
      default: A = vpT; B = wv16; C = WvT; break;
    }
    gemm_core<3, 128>(A, B, nullptr, C, 512, 512, 512, As, Bs);
  } else {
    if (blockIdx.x >= 2 || blockIdx.y != 0) return;
    const int zz = z - 3;
    const float* b1; const f16* WT; const float* b2;
    switch (zz) {
      case 0: b1 = wq_b; WT = qpT; b2 = qp_b; break;
      case 1: b1 = wk_b; WT = kpT; b2 = kp_b; break;
      default: b1 = wv_b; WT = vpT; b2 = vp_b; break;
    }
    const int o = blockIdx.x * 256 + threadIdx.x;
    const f16* row = WT + (size_t)o * 512;
    float s = 0.f;
    #pragma unroll 8
    for (int m = 0; m < 512; ++m)
      s += b1[m] * (float)row[m];
    const float sc = (zz == 0) ? C_SCALE : 1.0f;
    bc[zz * 512 + o] = (s + b2[o]) * sc;
  }
}

// ---------------- fused QKV projection (z = 0:q, 1:k, 2:v-transposed) ----------------
__global__ __launch_bounds__(256) void gemm_qkv_kernel(
    const f16* __restrict__ x,
    const f16* __restrict__ WqT, const f16* __restrict__ WkT, const f16* __restrict__ WvT,
    const float* __restrict__ bc,
    f16* __restrict__ q_f, f16* __restrict__ k_f, f16* __restrict__ vT)
{
  __shared__ __attribute__((aligned(16))) f16 As[128 * 32];
  __shared__ __attribute__((aligned(16))) f16 Bs[64 * 32];
  const int z = blockIdx.z;
  if (z == 2)
    gemm_core<1, 128>(x, WvT, bc + 1024, vT, 4096, 512, 512, As, Bs);
  else if (z == 1)
    gemm_core<0, 128>(x, WkT, bc + 512, k_f, 4096, 512, 512, As, Bs);
  else
    gemm_core<0, 128>(x, WqT, bc, q_f, 4096, 512, 512, As, Bs);
}

// ---------------- sp bias precompute ----------------
// value = log2(1 + 0.5*softmax(sp, axis=-1))   [f16; consumed as exp2 logit offset]
// layout: bt[((q>>5)*128 + (kv>>5))*1024 + ((kv>>4)&1)*512 + (q&31)*16 + (kv&15)]
__global__ __launch_bounds__(512) void sp_bias_kernel(
    const float* __restrict__ spg, f16* __restrict__ bt)
{
  __shared__ __attribute__((aligned(16))) f16 ex[16 * 4104];  // row stride 8208B (16B mult)
  __shared__ float sums[16];
  const int t = threadIdx.x;

  {
    const int row = t >> 5, j = t & 31;
    const float4* srow = (const float4*)(spg + (size_t)(blockIdx.x * 16 + row) * L_SEQ);
    f16* dst = ex + row * 4104;
    float ssum = 0.f;
    #pragma unroll 4
    for (int c = 0; c < 32; ++c) {
      float4 v = srow[c * 32 + j];
      float e0 = __expf(v.x), e1 = __expf(v.y), e2 = __expf(v.z), e3 = __expf(v.w);
      ssum += (e0 + e1) + (e2 + e3);
      f16x4 u;
      u[0] = (f16)e0; u[1] = (f16)e1; u[2] = (f16)e2; u[3] = (f16)e3;
      *(f16x4*)&dst[(c * 32 + j) * 4] = u;
    }
    ssum += __shfl_xor(ssum, 1, 64);
    ssum += __shfl_xor(ssum, 2, 64);
    ssum += __shfl_xor(ssum, 4, 64);
    ssum += __shfl_xor(ssum, 8, 64);
    ssum += __shfl_xor(ssum, 16, 64);
    if (j == 0) sums[row] = ssum;
  }
  __syncthreads();

  const int hi = t & 1, qloc = (t >> 1) & 15, s16 = (t >> 5) & 1;
  const float sc = 0.5f / sums[qloc];
  const int qt5 = blockIdx.x >> 1;
  const int q31 = ((blockIdx.x & 1) << 4) + qloc;
  const f16* exr = ex + qloc * 4104 + s16 * 16 + hi * 8;
  f16* ob = bt + (size_t)qt5 * 131072 + s16 * 512 + q31 * 16 + hi * 8;
  #pragma unroll 4
  for (int i = 0; i < 16; ++i) {
    const int kt5 = (t >> 6) + i * 8;
    f16x8 v = *(const f16x8*)&exr[kt5 * 32];
    f16x8 u;
    #pragma unroll
    for (int e = 0; e < 8; ++e)
      u[e] = (f16)__log2f(fmaf((float)v[e], sc, 1.0f));
    *(f16x8*)&ob[(size_t)kt5 * 1024] = u;
  }
}

// ---------------- fused attention, 32x32x16 MFMA, in-register P ----------------
// grid = 1024 linear blocks; all 8 heads of a (qtile,z) group share id%8 (XCD coloc).
// 4 waves; wave owns 32 q rows. Swapped QK^T + kv-row-permuted K keeps P in-lane.
// Q pre-scaled by 0.125*log2e upstream -> logit = s + L; packed-f16 exp path.
// setprio(1) around MFMA clusters (T5); first QK MFMA reads zz as C (no re-zeroing).
__global__ __launch_bounds__(256, 4) void attn3_kernel(
    const f16* __restrict__ qg, const f16* __restrict__ kg,
    const f16* __restrict__ vTg, const f16* __restrict__ bt,
    f16* __restrict__ opart, float* __restrict__ rspart)
{
  __shared__ __attribute__((aligned(16))) f16 Ks[2 * 4096];
  __shared__ __attribute__((aligned(16))) f16 Vs[2 * 4096];

  const int t = threadIdx.x;
  const int w = t >> 6, lane = t & 63;
  const int l31 = lane & 31, hi = lane >> 5;
  // XCD-coloc decomposition: b = (g%8) + 8*h + 64*(g/8); g = qt + 32*z
  const int b = blockIdx.x;
  const int h = (b >> 3) & 7;
  const int g = (b & 7) + ((b >> 6) << 3);
  const int qt = g & 31;
  const int z = g >> 5;
  const int q0w = qt * 128 + w * 32;
  const int kvbase = z * (L_SEQ / KVSPLIT);
  const int NST = (L_SEQ / KVSPLIT) / 64;

  // Q B-fragments (persist): qf[dk] = (C*Q)[q0w+l31][h*64 + dk*16 + hi*8 ..+8]
  f16x8 qf[4];
  #pragma unroll
  for (int dk = 0; dk < 4; ++dk)
    qf[dk] = *(const f16x8*)&qg[(size_t)(q0w + l31) * D_MODEL + h * 64 + dk * 16 + hi * 8];

  // staging source addresses (XOR-swizzle pre-applied on global side; LDS writes linear)
  const int srow0 = t >> 3, srow1 = 32 + (t >> 3), q16 = t & 7;
  const f16* ksrc0 = kg + h * 64 + (size_t)(kvbase + srow0) * D_MODEL + ((q16 ^ (srow0 & 7)) * 8);
  const f16* ksrc1 = kg + h * 64 + (size_t)(kvbase + srow1) * D_MODEL + ((q16 ^ (srow1 & 7)) * 8);
  const f16* vsrc0 = vTg + (size_t)(h * 64 + srow0) * L_SEQ + kvbase + (q16 ^ (srow0 & 7)) * 8;
  const f16* vsrc1 = vTg + (size_t)(h * 64 + srow1) * L_SEQ + kvbase + (q16 ^ (srow1 & 7)) * 8;

  #define STAGE(buf, stp)                                                      \
    do {                                                                       \
      const size_t ko = (size_t)(stp) * 64 * D_MODEL, vo = (size_t)(stp) * 64; \
      gload16(ksrc0 + ko, &Ks[(buf) * 4096 + w * 512]);                        \
      gload16(ksrc1 + ko, &Ks[(buf) * 4096 + 2048 + w * 512]);                 \
      gload16(vsrc0 + vo, &Vs[(buf) * 4096 + w * 512]);                        \
      gload16(vsrc1 + vo, &Vs[(buf) * 4096 + 2048 + w * 512]);                 \
    } while (0)

  // K A-row permutation: swap bits 2<->3 of l31
  const int sw23 = (l31 & ~12) | ((l31 & 4) << 1) | ((l31 & 8) >> 1);
  const int r7 = sw23 & 7;
  const int krow0 = sw23 * 64, krow1 = krow0 + 2048;        // jj=0 / jj=1 row bases (f16)
  const int vr7 = l31 & 7;
  const int vrow0 = l31 * 64, vrow1 = vrow0 + 2048;         // dg=0 / dg=1

  // bias base: ((qt5*128 + kt5)*2 + s16)*512 + l31*16 + hi*8
  const f16* bb = bt + (size_t)(q0w >> 5) * 131072 + l31 * 16 + hi * 8;
  const int kvb5 = kvbase >> 5;

  f32x16 zz = {0,0,0,0,0,0,0,0,0,0,0,0,0,0,0,0};
  f32x16 o0 = zz, o1 = zz;
  float rs0 = 0.f, rs1 = 0.f;
  const fp16x2 one2 = {(__fp16)1.0f, (__fp16)1.0f};

  STAGE(0, 0);
  __syncthreads();

  for (int st = 0; st < NST; ++st) {
    const int buf = st & 1;

    // ---- 1. bias (log2-domain) loads FIRST (oldest in vmcnt queue) ----
    const f16* bs = bb + (size_t)(kvb5 + st * 2) * 1024;
    f16x8 bl[4];   // [jj*2 + s16]
    bl[0] = *(const f16x8*)(bs);
    bl[1] = *(const f16x8*)(bs + 512);
    bl[2] = *(const f16x8*)(bs + 1024);
    bl[3] = *(const f16x8*)(bs + 1536);
    __builtin_amdgcn_sched_barrier(0);   // pin: bias issue precedes STAGE

    // ---- 2. prefetch next tile (stays in flight past the bias wait) ----
    if (st + 1 < NST) STAGE(buf ^ 1, st + 1);

    // ---- 3. S^T = K @ Q^T (swapped); first MFMA consumes zz (no re-zero movs) ----
    f32x16 s0, s1;
    const f16* kb = &Ks[buf * 4096];
    __builtin_amdgcn_s_setprio(1);
    {
      const int ch0 = (hi ^ r7) * 8;     // dk=0
      f16x8 k0 = *(const f16x8*)&kb[krow0 + ch0];
      f16x8 k1 = *(const f16x8*)&kb[krow1 + ch0];
      s0 = __builtin_amdgcn_mfma_f32_32x32x16_f16(k0, qf[0], zz, 0, 0, 0);
      s1 = __builtin_amdgcn_mfma_f32_32x32x16_f16(k1, qf[0], zz, 0, 0, 0);
    }
    #pragma unroll
    for (int dk = 1; dk < 4; ++dk) {
      const int ch = ((dk * 2 + hi) ^ r7) * 8;
      f16x8 k0 = *(const f16x8*)&kb[krow0 + ch];
      f16x8 k1 = *(const f16x8*)&kb[krow1 + ch];
      s0 = __builtin_amdgcn_mfma_f32_32x32x16_f16(k0, qf[dk], s0, 0, 0, 0);
      s1 = __builtin_amdgcn_mfma_f32_32x32x16_f16(k1, qf[dk], s1, 0, 0, 0);
    }
    __builtin_amdgcn_s_setprio(0);

    // ---- 4. p = exp2(s + L), fully packed f16; pairs land directly in PV frags ----
    f16x8 pa[4];   // [kk] : kv = kk*16 + hi*8 + e
    #pragma unroll
    for (int q = 0; q < 4; ++q) {
      const f32x16& s = (q >> 1) ? s1 : s0;
      const int sh = q & 1;
      union { f16x8 v; fp16x2 h2[4]; } ub; ub.v = bl[q];
      union { fp16x2 h2[4]; f16x8 v; } up;
      #pragma unroll
      for (int e2 = 0; e2 < 4; ++e2) {
        fp16x2 s2 = __builtin_amdgcn_cvt_pkrtz(s[sh * 8 + e2 * 2], s[sh * 8 + e2 * 2 + 1]);
        __half2 p2 = h2exp2(__hadd2(bitcast<__half2>(s2), bitcast<__half2>(ub.h2[e2])));
        fp16x2 pp = bitcast<fp16x2>(p2);
        up.h2[e2] = pp;
        if (e2 & 1) rs1 = __builtin_amdgcn_fdot2(pp, one2, rs1, false);
        else        rs0 = __builtin_amdgcn_fdot2(pp, one2, rs0, false);
      }
      pa[q] = up.v;
    }

    // ---- 5. O += P @ V ----
    const f16* vb = &Vs[buf * 4096];
    __builtin_amdgcn_s_setprio(1);
    #pragma unroll
    for (int kk = 0; kk < 4; ++kk) {
      const int ch = ((kk * 2 + hi) ^ vr7) * 8;
      f16x8 v0 = *(const f16x8*)&vb[vrow0 + ch];
      f16x8 v1 = *(const f16x8*)&vb[vrow1 + ch];
      o0 = __builtin_amdgcn_mfma_f32_32x32x16_f16(pa[kk], v0, o0, 0, 0, 0);
      o1 = __builtin_amdgcn_mfma_f32_32x32x16_f16(pa[kk], v1, o1, 0, 0, 0);
    }
    __builtin_amdgcn_s_setprio(0);
    __syncthreads();   // drains prefetch (had full exp+PV to land) + buf handoff
  }
  #undef STAGE

  // ---- epilogue: partial O (f16) + partial rowsums ----
  float rs = rs0 + rs1;
  rs += __shfl_xor(rs, 32, 64);
  f16* op = opart + (size_t)z * (L_SEQ * D_MODEL);
  #pragma unroll
  for (int dg = 0; dg < 2; ++dg) {
    const f32x16& o = dg ? o1 : o0;
    #pragma unroll
    for (int r = 0; r < 16; ++r) {
      const int q = q0w + (r & 3) + 8 * (r >> 2) + 4 * hi;
      op[(size_t)q * D_MODEL + h * 64 + dg * 32 + l31] = (f16)o[r];
    }
  }
  if (hi == 0)
    rspart[((size_t)z * 8 + h) * L_SEQ + q0w + l31] = rs;
}

// ---------------- combine kv-split partials -> normalized f16 ----------------
__global__ void combine4_kernel(const f16* __restrict__ opart,
                                const float* __restrict__ rspart,
                                f16* __restrict__ attout)
{
  const int idx = blockIdx.x * 256 + threadIdx.x;  // 262144
  const int q = idx >> 6;
  const int d = (idx & 63) << 3;
  const int h = d >> 6;
  float rsum = 0.f;
  #pragma unroll
  for (int zz = 0; zz < KVSPLIT; ++zz)
    rsum += rspart[((size_t)zz * 8 + h) * L_SEQ + q];
  const float inv = 1.f / rsum;
  float acc[8] = {0,0,0,0,0,0,0,0};
  #pragma unroll
  for (int zz = 0; zz < KVSPLIT; ++zz) {
    f16x8 v = *(const f16x8*)&opart[(size_t)zz * (L_SEQ * D_MODEL) + (size_t)q * D_MODEL + d];
    #pragma unroll
    for (int e = 0; e < 8; ++e) acc[e] += (float)v[e];
  }
  f16x8 u;
  #pragma unroll
  for (int e = 0; e < 8; ++e) u[e] = (f16)(acc[e] * inv);
  *(f16x8*)&attout[(size_t)q * D_MODEL + d] = u;
}

// ---------------- host ----------------
extern "C" void kernel_launch(void* const* d_in, const int* in_sizes, int n_in,
                              void* d_out, int out_size, void* d_ws, size_t ws_size,
                              hipStream_t stream)
{
  (void)in_sizes; (void)n_in; (void)out_size; (void)ws_size;

  const float* x    = (const float*)d_in[0];
  const float* sp   = (const float*)d_in[1];
  const float* wq_w = (const float*)d_in[2];
  const float* wq_b = (const float*)d_in[3];
  const float* wk_w = (const float*)d_in[4];
  const float* wk_b = (const float*)d_in[5];
  const float* wv_w = (const float*)d_in[6];
  const float* wv_b = (const float*)d_in[7];
  const float* qp_w = (const float*)d_in[8];
  const float* qp_b = (const float*)d_in[9];
  const float* kp_w = (const float*)d_in[10];
  const float* kp_b = (const float*)d_in[11];
  const float* vp_w = (const float*)d_in[12];
  const float* vp_b = (const float*)d_in[13];
  const float* out_w = (const float*)d_in[14];
  const float* out_b = (const float*)d_in[15];

  const size_t MB = 1048576;
  char* ws = (char*)d_ws;
  // phase 1 (dead before attn) -- overlapped by opart:
  f16*   x_f    = (f16*)(ws + 0);              // 4 MiB
  f16*   qpT    = (f16*)(ws + 4 * MB);
  f16*   kpT    = (f16*)(ws + 4 * MB + 524288);
  f16*   vpT    = (f16*)(ws + 5 * MB);
  f16*   wq16   = (f16*)(ws + 6 * MB);
  f16*   wk16   = (f16*)(ws + 6 * MB + 524288);
  f16*   wv16   = (f16*)(ws + 7 * MB);
  f16*   WqT    = (f16*)(ws + 7 * MB + 524288);
  f16*   WkT    = (f16*)(ws + 8 * MB);
  f16*   WvT    = (f16*)(ws + 8 * MB + 524288);
  float* bc     = (float*)(ws + 9 * MB);       // 3*512 f32
  // attn phase:
  f16*   opart  = (f16*)(ws + 0);              // 16 MiB (over phase-1 buffers)
  f16*   q_f    = (f16*)(ws + 16 * MB);        // 4 MiB; attout overlays after attn
  f16*   attout = (f16*)(ws + 16 * MB);
  f16*   k_f    = (f16*)(ws + 20 * MB);
  f16*   vT     = (f16*)(ws + 24 * MB);
  float* rspart = (float*)(ws + 28 * MB);      // 512 KiB
  f16*   bt     = (f16*)(ws + 28 * MB + 524288); // 32 MiB -> ends 60.5 MiB
  // outT lives OUTSIDE opart's range (consumed by the FINAL gemm, after attn3
  // has overwritten ws[0..16MB) with opart)
  f16*   outT   = (f16*)(ws + 60 * MB + 524288); // 512 KiB, ends 61 MiB

  prep_kernel<<<1728, 256, 0, stream>>>(x, wq_w, wk_w, wv_w,
                                        qp_w, kp_w, vp_w, out_w,
                                        x_f, wq16, wk16, wv16,
                                        qpT, kpT, vpT, outT);
  sp_bias_kernel<<<256, 512, 0, stream>>>(sp, bt);

  wbcombine_kernel<<<dim3(4, 8, 6), 256, 0, stream>>>(
      qpT, kpT, vpT, wq16, wk16, wv16, WqT, WkT, WvT,
      wq_b, wk_b, wv_b, qp_b, kp_b, vp_b, bc);

  gemm_qkv_kernel<<<dim3(32, 8, 3), 256, 0, stream>>>(x_f, WqT, WkT, WvT, bc,
                                                      q_f, k_f, vT);

  attn3_kernel<<<dim3(1024), 256, 0, stream>>>(q_f, k_f, vT, bt,
                                               opart, rspart);
  combine4_kernel<<<1024, 256, 0, stream>>>(opart, rspart, attout);

  gemm_bt_kernel<2, 64><<<dim3(64, 8), 256, 0, stream>>>(attout, outT, out_b,
                                                         d_out, 4096, 512, 512);
}